// Round 6
// baseline (309.897 us; speedup 1.0000x reference)
//
#include <hip/hip_runtime.h>

using bf16x8 = __attribute__((ext_vector_type(8))) __bf16;
using f32x4  = __attribute__((ext_vector_type(4))) float;
using f32x16 = __attribute__((ext_vector_type(16))) float;
typedef __attribute__((ext_vector_type(2))) unsigned u32x2;
typedef __attribute__((ext_vector_type(4))) unsigned u32x4;

#define DEV __device__ __forceinline__

DEV unsigned short f2bf(float f){
  unsigned u = __builtin_bit_cast(unsigned, f);
  u += 0x7fffu + ((u >> 16) & 1u);
  return (unsigned short)(u >> 16);
}

DEV void load_lds16(const void* g, void* l){
  __builtin_amdgcn_global_load_lds((const __attribute__((address_space(1))) unsigned*)g,
                                   (__attribute__((address_space(3))) unsigned*)l, 16, 0, 0);
}

DEV f32x4 mfma16(bf16x8 a, bf16x8 b, f32x4 c){
  return __builtin_amdgcn_mfma_f32_16x16x32_bf16(a, b, c, 0, 0, 0);
}

DEV f32x16 mfma32(bf16x8 a, bf16x8 b, f32x16 c){
  return __builtin_amdgcn_mfma_f32_32x32x16_bf16(a, b, c, 0, 0, 0);
}

DEV float exp2_hw(float x){
  float r;
  asm("v_exp_f32 %0, %1" : "=v"(r) : "v"(x));
  return r;
}

DEV unsigned cvtpk_bf16(float a, float b){
  unsigned r;
  asm("v_cvt_pk_bf16_f32 %0, %1, %2" : "=v"(r) : "v"(a), "v"(b));
  return r;
}

DEV void permswap(unsigned &a, unsigned &b){
  asm volatile("v_permlane32_swap_b32 %0, %1" : "+v"(a), "+v"(b));
}

// ---------------- weight fp32 -> bf16 ----------------
__global__ void wconv_k(const float* __restrict__ a, unsigned short* __restrict__ o, int n4){
  for (int i = blockIdx.x * blockDim.x + threadIdx.x; i < n4; i += gridDim.x * blockDim.x){
    float4 v = reinterpret_cast<const float4*>(a)[i];
    ushort4 u;
    u.x = f2bf(v.x); u.y = f2bf(v.y); u.z = f2bf(v.z); u.w = f2bf(v.w);
    reinterpret_cast<ushort4*>(o)[i] = u;
  }
}

// ---------------- GroupNorm stats ----------------
__global__ __launch_bounds__(256) void gn_stats_k(const float* __restrict__ x, float* __restrict__ st){
  int bg = blockIdx.x; // b*32+g
  const float4* xp = reinterpret_cast<const float4*>(x + (size_t)bg * 32768);
  float s = 0.f, ss = 0.f;
  for (int i = threadIdx.x; i < 8192; i += 256){
    float4 v = xp[i];
    s  += (v.x + v.y) + (v.z + v.w);
    ss += (v.x*v.x + v.y*v.y) + (v.z*v.z + v.w*v.w);
  }
  #pragma unroll
  for (int off = 32; off; off >>= 1){ s += __shfl_down(s, off); ss += __shfl_down(ss, off); }
  __shared__ float rs[4], rss[4];
  if ((threadIdx.x & 63) == 0){ rs[threadIdx.x >> 6] = s; rss[threadIdx.x >> 6] = ss; }
  __syncthreads();
  if (threadIdx.x == 0){
    s  = (rs[0] + rs[1]) + (rs[2] + rs[3]);
    ss = (rss[0] + rss[1]) + (rss[2] + rss[3]);
    float mu  = s * (1.0f / 32768.0f);
    float var = ss * (1.0f / 32768.0f) - mu * mu;
    st[bg*2]   = mu;
    st[bg*2+1] = rsqrtf(var + 1e-5f);
  }
}

// ---------------- GN apply ----------------
__global__ __launch_bounds__(256) void gn_norm_k(const float* __restrict__ x,
                                                 const float* __restrict__ gw,
                                                 const float* __restrict__ gb,
                                                 const float* __restrict__ st,
                                                 float* __restrict__ xn,
                                                 unsigned short* __restrict__ xnt){
  int t = blockIdx.x;            // B*G*16 = 4096
  int tile = t & 15; int g = (t >> 4) & 31; int bb = t >> 9;
  float mu = st[(bb*32+g)*2], rstd = st[(bb*32+g)*2+1];
  __shared__ unsigned short lt[64*32];
  int tid = threadIdx.x;
  int l = tid & 63;
  int c0 = tid >> 6;
  size_t base = ((size_t)bb*1024 + g*32) * 1024 + tile*64;
  #pragma unroll
  for (int cb = 0; cb < 8; ++cb){
    int c = cb*4 + c0;
    size_t idx = base + (size_t)c*1024 + l;
    float xv = x[idx];
    int cg = g*32 + c;
    float v = (xv - mu) * rstd * gw[cg] + gb[cg];
    xn[idx] = v;
    lt[l*32 + c] = f2bf(v);
  }
  __syncthreads();
  int lr = tid >> 2, sl = tid & 3;
  uint4 u = *reinterpret_cast<uint4*>(&lt[lr*32 + sl*8]);
  size_t ob = ((size_t)bb*1024 + tile*64 + lr) * 1024 + g*32 + sl*8;
  *reinterpret_cast<uint4*>(&xnt[ob]) = u;
}

// ---------------- QKV GEMM: 256x256 tile, counted-vmcnt 4-phase pipeline ----------------
// Phase p=(kh,mh): consumes A-unit(kh,mh) [8KB,1 load] + B-unit(kh) [16KB,2 loads, reg-reused
// across the mh pair]. Tile t+1 staged during tile t in fixed order
// [B(k0)x2, A(k0,0), A(k0,1), B(k1)x2, A(k1,0), A(k1,1)] into the other buffer.
// Derived waits (lag >= 3 phases): vmcnt 5,6,5,6; tail tile: 5,4,1,0.
__global__ __launch_bounds__(512, 2) void gemm8_k(const unsigned short* __restrict__ A,
                                                  const unsigned short* __restrict__ Bm,
                                                  const float* __restrict__ bias,
                                                  unsigned short* __restrict__ qo,
                                                  unsigned short* __restrict__ ko,
                                                  unsigned short* __restrict__ vo){
  __shared__ char sA[2][32768];
  __shared__ char sB[2][32768];
  const int tid = threadIdx.x;
  const int w = tid >> 6, ln = tid & 63, hi = ln >> 4, lo = ln & 15;
  const int wm = w >> 2, wn = w & 3;              // 2M x 4N waves
  const int bxo = (int)blockIdx.x;
  // XCD chunk = 6mt x 8nt (grid 12x32 = 2x4 chunks of 6x8)
  const int xcd = bxo & 7, idx = bxo >> 3;        // idx 0..47
  const int mt = (xcd >> 2)*6 + (idx % 6);
  const int nt = (xcd & 3)*8 + (idx / 6);
  const char* Ag = (const char*)A + (size_t)mt*256*2048;
  const char* Bg = (const char*)Bm + (size_t)nt*256*2048;
  f32x4 acc[8][4] = {};

  // A-unit (kh,mh): 8KB at sA + (kh*2+mh)*8192. local row lr(0..127) -> global row
  // r = mh*64 + (lr&63) + ((lr&64)<<1)  (both wm stripes). Row = 64B (32 K-elems).
  // Swizzle key = (lr>>1)&3 on the 16B slot (2-way bank aliasing = free).
  auto stageA = [&](int buf, int kt, int kh, int mh){
    const int lr = tid >> 2;
    const int cslot = (tid & 3) ^ ((lr >> 1) & 3);
    const int r = mh*64 + (lr & 63) + ((lr & 64) << 1);
    load_lds16(Ag + (size_t)r*2048 + kt*128 + kh*64 + cslot*16,
               sA[buf] + (kh*2 + mh)*8192 + tid*16);
  };
  // B-unit kh: 16KB at sB + kh*16384, rows r=0..255 (n), 64B rows, same swizzle.
  auto stageB = [&](int buf, int kt, int kh, int i){
    const int s = tid*16 + i*8192;
    const int r = s >> 6;
    const int cslot = ((s >> 4) & 3) ^ ((r >> 1) & 3);
    load_lds16(Bg + (size_t)r*2048 + kt*128 + kh*64 + cslot*16,
               sB[buf] + kh*16384 + s);
  };
  auto readA = [&](const char* base, int kh, int mh, int mi){
    const int lr = wm*64 + mi*16 + lo;
    return *reinterpret_cast<const bf16x8*>(base + (kh*2 + mh)*8192 + lr*64 + ((hi ^ ((lr >> 1) & 3)) << 4));
  };
  auto readB = [&](const char* base, int kh, int ni){
    const int r = wn*64 + ni*16 + lo;
    return *reinterpret_cast<const bf16x8*>(base + kh*16384 + r*64 + ((hi ^ ((r >> 1) & 3)) << 4));
  };

  // prologue: stage tile 0 in canonical issue order
  stageB(0, 0, 0, 0); stageB(0, 0, 0, 1);
  stageA(0, 0, 0, 0); stageA(0, 0, 0, 1);
  stageB(0, 0, 1, 0); stageB(0, 0, 1, 1);
  stageA(0, 0, 1, 0); stageA(0, 0, 1, 1);

  bf16x8 a[4], b[4];
  #define MFMA_CLUSTER(AOFF)                                        \
    __builtin_amdgcn_s_setprio(1);                                  \
    _Pragma("unroll")                                               \
    for (int mi = 0; mi < 4; ++mi)                                  \
      _Pragma("unroll")                                             \
      for (int ni = 0; ni < 4; ++ni)                                \
        acc[AOFF + mi][ni] = mfma16(a[mi], b[ni], acc[AOFF + mi][ni]); \
    __builtin_amdgcn_s_setprio(0);

  for (int t = 0; t < 15; ++t){
    const int cur = t & 1, nxt = cur ^ 1, tn = t + 1;
    const char* sAc = sA[cur];
    const char* sBc = sB[cur];
    // ---- phase 0: (k0, m0) ----
    asm volatile("s_waitcnt vmcnt(5)" ::: "memory");
    __builtin_amdgcn_s_barrier();
    stageB(nxt, tn, 0, 0); stageB(nxt, tn, 0, 1);
    #pragma unroll
    for (int ni = 0; ni < 4; ++ni) b[ni] = readB(sBc, 0, ni);
    #pragma unroll
    for (int mi = 0; mi < 4; ++mi) a[mi] = readA(sAc, 0, 0, mi);
    MFMA_CLUSTER(0)
    // ---- phase 1: (k0, m1) ----
    asm volatile("s_waitcnt vmcnt(6)" ::: "memory");
    __builtin_amdgcn_s_barrier();
    stageA(nxt, tn, 0, 0); stageA(nxt, tn, 0, 1);
    #pragma unroll
    for (int mi = 0; mi < 4; ++mi) a[mi] = readA(sAc, 0, 1, mi);
    MFMA_CLUSTER(4)
    // ---- phase 2: (k1, m0) ----
    asm volatile("s_waitcnt vmcnt(5)" ::: "memory");
    __builtin_amdgcn_s_barrier();
    stageB(nxt, tn, 1, 0); stageB(nxt, tn, 1, 1);
    #pragma unroll
    for (int ni = 0; ni < 4; ++ni) b[ni] = readB(sBc, 1, ni);
    #pragma unroll
    for (int mi = 0; mi < 4; ++mi) a[mi] = readA(sAc, 1, 0, mi);
    MFMA_CLUSTER(0)
    // ---- phase 3: (k1, m1) ----
    asm volatile("s_waitcnt vmcnt(6)" ::: "memory");
    __builtin_amdgcn_s_barrier();
    stageA(nxt, tn, 1, 0); stageA(nxt, tn, 1, 1);
    #pragma unroll
    for (int mi = 0; mi < 4; ++mi) a[mi] = readA(sAc, 1, 1, mi);
    MFMA_CLUSTER(4)
  }
  { // ---- tail tile t=15 (no staging; waits tightened) ----
    const char* sAc = sA[1];
    const char* sBc = sB[1];
    asm volatile("s_waitcnt vmcnt(5)" ::: "memory");
    __builtin_amdgcn_s_barrier();
    #pragma unroll
    for (int ni = 0; ni < 4; ++ni) b[ni] = readB(sBc, 0, ni);
    #pragma unroll
    for (int mi = 0; mi < 4; ++mi) a[mi] = readA(sAc, 0, 0, mi);
    MFMA_CLUSTER(0)
    asm volatile("s_waitcnt vmcnt(4)" ::: "memory");
    __builtin_amdgcn_s_barrier();
    #pragma unroll
    for (int mi = 0; mi < 4; ++mi) a[mi] = readA(sAc, 0, 1, mi);
    MFMA_CLUSTER(4)
    asm volatile("s_waitcnt vmcnt(1)" ::: "memory");
    __builtin_amdgcn_s_barrier();
    #pragma unroll
    for (int ni = 0; ni < 4; ++ni) b[ni] = readB(sBc, 1, ni);
    #pragma unroll
    for (int mi = 0; mi < 4; ++mi) a[mi] = readA(sAc, 1, 0, mi);
    MFMA_CLUSTER(0)
    asm volatile("s_waitcnt vmcnt(0)" ::: "memory");
    __builtin_amdgcn_s_barrier();
    #pragma unroll
    for (int mi = 0; mi < 4; ++mi) a[mi] = readA(sAc, 1, 1, mi);
    MFMA_CLUSTER(4)
  }
  #undef MFMA_CLUSTER

  // ---- epilogue: scatter to q/k/v with bias ----
  const int b8 = nt >> 2;
  #pragma unroll
  for (int m8 = 0; m8 < 8; ++m8){
    const int o0 = mt*256 + wm*128 + (m8 >> 2)*64 + (m8 & 3)*16 + hi*4;
    const int hh = o0 / 192;
    const int rr = o0 % 192;
    const size_t hb = (size_t)b8*16 + hh;
    float bv0 = bias[o0], bv1 = bias[o0+1], bv2 = bias[o0+2], bv3 = bias[o0+3];
    #pragma unroll
    for (int n4 = 0; n4 < 4; ++n4){
      const int l = (nt & 3)*256 + wn*64 + (n4 >> 1)*32 + (n4 & 1)*16 + lo;
      f32x4 v = acc[m8][n4];
      if (rr < 64){
        ushort4 u;
        u.x = f2bf(v[0] + bv0); u.y = f2bf(v[1] + bv1);
        u.z = f2bf(v[2] + bv2); u.w = f2bf(v[3] + bv3);
        *reinterpret_cast<ushort4*>(qo + (hb*1024 + l)*64 + rr) = u;
      } else if (rr < 128){
        ushort4 u;
        u.x = f2bf(v[0] + bv0); u.y = f2bf(v[1] + bv1);
        u.z = f2bf(v[2] + bv2); u.w = f2bf(v[3] + bv3);
        *reinterpret_cast<ushort4*>(ko + (hb*1024 + l)*64 + (rr - 64)) = u;
      } else {
        const int d = rr - 128;
        vo[(hb*64 + d + 0)*1024 + l] = f2bf(v[0] + bv0);
        vo[(hb*64 + d + 1)*1024 + l] = f2bf(v[1] + bv1);
        vo[(hb*64 + d + 2)*1024 + l] = f2bf(v[2] + bv2);
        vo[(hb*64 + d + 3)*1024 + l] = f2bf(v[3] + bv3);
      }
    }
  }
}

// ---------------- out-proj GEMM (128x128, 2-phase) ----------------
__global__ __launch_bounds__(256) void gemm_k(const unsigned short* __restrict__ A,
                                              const unsigned short* __restrict__ Bm,
                                              const float* __restrict__ bias,
                                              float* __restrict__ outf){
  constexpr int MT = 8;
  constexpr int CHUNK = MT * 8;
  __shared__ char sA[16384];
  __shared__ char sB[16384];
  const int tid = threadIdx.x;
  const int w = tid >> 6, ln = tid & 63, hi = ln >> 4, lo = ln & 15;
  const int wrow = w >> 1, wcol = w & 1;
  const int bxo = (int)blockIdx.x;
  const int bx = (bxo & 7) * CHUNK + (bxo >> 3);
  const int b = bx / (MT*8);
  const int rem = bx % (MT*8);
  const int mt = rem >> 3, nt = rem & 7;
  const char* Ag = (const char*)A + (size_t)mt*128*2048;
  const char* Bg = (const char*)Bm + ((size_t)b*1024 + nt*128)*2048;
  f32x4 acc[4][4] = {};
  for (int kk = 0; kk < 16; ++kk){
    #pragma unroll
    for (int i = 0; i < 4; ++i){
      int s = tid*16 + i*4096;
      int row = s >> 7;
      int byte = (s & 127) ^ ((row & 7) << 4);
      size_t off = (size_t)row*2048 + kk*128 + byte;
      load_lds16(Ag + off, sA + s);
      load_lds16(Bg + off, sB + s);
    }
    __syncthreads();
    #pragma unroll
    for (int ks = 0; ks < 2; ++ks){
      bf16x8 af[4], bq[4];
      #pragma unroll
      for (int mi = 0; mi < 4; ++mi){
        int row = wrow*64 + mi*16 + lo;
        af[mi] = *reinterpret_cast<const bf16x8*>(sA + row*128 + ((ks*64 + hi*16) ^ ((row & 7) << 4)));
      }
      #pragma unroll
      for (int ni = 0; ni < 4; ++ni){
        int row = wcol*64 + ni*16 + lo;
        bq[ni] = *reinterpret_cast<const bf16x8*>(sB + row*128 + ((ks*64 + hi*16) ^ ((row & 7) << 4)));
      }
      #pragma unroll
      for (int mi = 0; mi < 4; ++mi)
        #pragma unroll
        for (int ni = 0; ni < 4; ++ni)
          acc[mi][ni] = mfma16(af[mi], bq[ni], acc[mi][ni]);
    }
    __syncthreads();
  }
  #pragma unroll
  for (int mi = 0; mi < 4; ++mi){
    const int o0 = mt*128 + wrow*64 + mi*16 + hi*4;
    #pragma unroll
    for (int ni = 0; ni < 4; ++ni){
      const int l = nt*128 + wcol*64 + ni*16 + lo;
      #pragma unroll
      for (int r = 0; r < 4; ++r){
        size_t idx = ((size_t)b*1024 + o0 + r) * 1024 + l;
        outf[idx] += acc[mi][ni][r] + bias[o0 + r];
      }
    }
  }
}

// ---------------- flash attention: swapped QK^T 32x32, in-register softmax ----------------
__global__ __launch_bounds__(256) void attn_k(const unsigned short* __restrict__ qt,
                                              const unsigned short* __restrict__ kt,
                                              const unsigned short* __restrict__ vt,
                                              unsigned short* __restrict__ ctx){
  __shared__ char sK[2][8192];
  __shared__ char sV[2][8192];
  __shared__ float sRed[4][32];
  const int tid = threadIdx.x;
  const int w = tid >> 6, ln = tid & 63;
  const int hi5 = ln >> 5, lo5 = ln & 31;
  const int bxo = (int)blockIdx.x;
  const int bx = (bxo & 7) * 128 + (bxo >> 3);   // XCD swizzle
  const int qb = bx & 7;
  const int bh = bx >> 3;                        // b*16 + h
  const unsigned short* qp = qt + ((size_t)bh*1024 + qb*128 + w*32 + lo5) * 64;
  bf16x8 qreg[4];
  #pragma unroll
  for (int d = 0; d < 4; ++d)
    qreg[d] = *reinterpret_cast<const bf16x8*>(qp + d*16 + hi5*8);
  const char* kg = (const char*)(kt + (size_t)bh*65536);
  const char* vg = (const char*)(vt + (size_t)bh*65536);
  f32x16 oa0 = {}, oa1 = {};
  float m = 0.f, l = 0.f;

  auto STAGE = [&](int buf, int kb){
    #pragma unroll
    for (int i = 0; i < 2; ++i){
      int s = tid*16 + i*4096;
      int row = s >> 7;
      int byte = (s & 127) ^ ((row & 7) << 4);
      load_lds16(kg + (size_t)(kb*64 + row)*128 + byte, sK[buf] + s);
      load_lds16(vg + (size_t)row*2048 + kb*128 + byte, sV[buf] + s);
    }
  };

  const float sc2 = 0.015625f * 1.44269504f;  // (1/64) * log2(e)

  STAGE(0, 0);
  asm volatile("s_waitcnt vmcnt(0)" ::: "memory");
  __builtin_amdgcn_s_barrier();

  for (int kb = 0; kb < 16; ++kb){
    const int cur = kb & 1;
    STAGE(cur ^ 1, (kb + 1) & 15);

    const char* kbase0 = sK[cur] + lo5*128;
    const char* kbase1 = sK[cur] + (32 + lo5)*128;
    const int ksw = (lo5 & 7) << 4;
    f32x16 s0 = {}, s1 = {};
    #pragma unroll
    for (int d = 0; d < 4; ++d){
      int off = (d*32 + hi5*16) ^ ksw;
      bf16x8 ka = *reinterpret_cast<const bf16x8*>(kbase0 + off);
      bf16x8 kb8 = *reinterpret_cast<const bf16x8*>(kbase1 + off);
      s0 = mfma32(ka, qreg[d], s0);
      s1 = mfma32(kb8, qreg[d], s1);
    }

    float t[16];
    #pragma unroll
    for (int i = 0; i < 16; ++i) t[i] = fmaxf(s0[i], s1[i]);
    #pragma unroll
    for (int st = 8; st; st >>= 1)
      #pragma unroll
      for (int i = 0; i < st; ++i) t[i] = fmaxf(t[i], t[i+st]);
    float mx = fmaxf(t[0], __shfl_xor(t[0], 32));
    float m2 = mx * sc2;

    if (__builtin_expect(__any(m2 > m + 8.f), 0)){
      float nm = fmaxf(m, m2);
      float corr = exp2_hw(m - nm);
      m = nm; l *= corr;
      sRed[w][lo5] = corr;
      __builtin_amdgcn_wave_barrier();
      #pragma unroll
      for (int r = 0; r < 16; ++r){
        float cc = sRed[w][(r & 3) + 8*(r >> 2) + 4*hi5];
        oa0[r] *= cc; oa1[r] *= cc;
      }
      __builtin_amdgcn_wave_barrier();
    }

    float ps[16];
    #pragma unroll
    for (int i = 0; i < 16; ++i){
      float p0 = exp2_hw(fmaf(s0[i], sc2, -m));
      float p1 = exp2_hw(fmaf(s1[i], sc2, -m));
      s0[i] = p0; s1[i] = p1;
      ps[i] = p0 + p1;
    }
    #pragma unroll
    for (int st = 8; st; st >>= 1)
      #pragma unroll
      for (int i = 0; i < st; ++i) ps[i] += ps[i+st];
    l += ps[0] + __shfl_xor(ps[0], 32);

    bf16x8 pa[4];
    #pragma unroll
    for (int sl = 0; sl < 4; ++sl){
      const int c0 = 2*(sl & 1), c1 = c0 + 1;
      unsigned w0, w1, w2, w3;
      if (sl < 2){
        w0 = cvtpk_bf16(s0[4*c0+0], s0[4*c0+1]);
        w1 = cvtpk_bf16(s0[4*c0+2], s0[4*c0+3]);
        w2 = cvtpk_bf16(s0[4*c1+0], s0[4*c1+1]);
        w3 = cvtpk_bf16(s0[4*c1+2], s0[4*c1+3]);
      } else {
        w0 = cvtpk_bf16(s1[4*c0+0], s1[4*c0+1]);
        w1 = cvtpk_bf16(s1[4*c0+2], s1[4*c0+3]);
        w2 = cvtpk_bf16(s1[4*c1+0], s1[4*c1+1]);
        w3 = cvtpk_bf16(s1[4*c1+2], s1[4*c1+3]);
      }
      permswap(w0, w2);
      permswap(w1, w3);
      u32x4 pc; pc.x = w0; pc.y = w1; pc.z = w2; pc.w = w3;
      pa[sl] = __builtin_bit_cast(bf16x8, pc);
    }

    const char* vb0 = sV[cur] + lo5*128;
    const char* vb1 = sV[cur] + (32 + lo5)*128;
    #pragma unroll
    for (int sl = 0; sl < 4; ++sl){
      int off = (sl*32 + hi5*16) ^ ksw;
      bf16x8 v0 = *reinterpret_cast<const bf16x8*>(vb0 + off);
      bf16x8 v1 = *reinterpret_cast<const bf16x8*>(vb1 + off);
      oa0 = mfma32(pa[sl], v0, oa0);
      oa1 = mfma32(pa[sl], v1, oa1);
    }

    asm volatile("s_waitcnt vmcnt(0)" ::: "memory");
    __builtin_amdgcn_s_barrier();
  }

  sRed[w][lo5] = l;
  __builtin_amdgcn_wave_barrier();
  const int b = bh >> 4, h = bh & 15;
  #pragma unroll
  for (int r = 0; r < 16; ++r){
    int ql = (r & 3) + 8*(r >> 2) + 4*hi5;
    float inv = __builtin_amdgcn_rcpf(sRed[w][ql]);
    size_t rowb = ((size_t)b*1024 + qb*128 + w*32 + ql) * 1024 + h*64;
    ctx[rowb + lo5]      = f2bf(oa0[r] * inv);
    ctx[rowb + 32 + lo5] = f2bf(oa1[r] * inv);
  }
}

extern "C" void kernel_launch(void* const* d_in, const int* in_sizes, int n_in,
                              void* d_out, int out_size, void* d_ws, size_t ws_size,
                              hipStream_t stream) {
  (void)in_sizes; (void)n_in; (void)out_size; (void)ws_size;
  const float* x     = (const float*)d_in[0];
  const float* gn_w  = (const float*)d_in[1];
  const float* gn_b  = (const float*)d_in[2];
  const float* qkv_w = (const float*)d_in[3];
  const float* qkv_b = (const float*)d_in[4];
  const float* out_w = (const float*)d_in[5];
  const float* out_b = (const float*)d_in[6];
  // d_in[7] = qk_bias scalar: softmax(x+c)==softmax(x) -> no-op.
  float* out = (float*)d_out;
  char* ws = (char*)d_ws;
  unsigned short* xnt  = (unsigned short*)(ws);               // 16 MiB  xn^T  [b][l][c]
  unsigned short* qwb  = (unsigned short*)(ws + 16777216);    // 6 MiB   qkv_w bf16
  unsigned short* owb  = (unsigned short*)(ws + 23068672);    // 2 MiB   out_w bf16
  unsigned short* qt   = (unsigned short*)(ws + 25165824);    // 16 MiB  q [b][h][l][d]
  unsigned short* kt   = (unsigned short*)(ws + 41943040);    // 16 MiB  k [b][h][l][d]
  unsigned short* vs   = (unsigned short*)(ws + 58720256);    // 16 MiB  v [b][h][d][l]
  unsigned short* ctxt = (unsigned short*)(ws + 75497472);    // 16 MiB  ctx^T [b][l][c]
  float*          st   = (float*)(ws + 92274688);             // 2 KiB   GN stats

  wconv_k<<<512, 256, 0, stream>>>(qkv_w, qwb, 786432);
  wconv_k<<<512, 256, 0, stream>>>(out_w, owb, 262144);
  gn_stats_k<<<256, 256, 0, stream>>>(x, st);
  gn_norm_k<<<4096, 256, 0, stream>>>(x, gn_w, gn_b, st, out, xnt);
  gemm8_k<<<384, 512, 0, stream>>>(qwb, xnt, qkv_b, qt, kt, vs);
  attn_k<<<1024, 256, 0, stream>>>(qt, kt, vs, ctxt);
  gemm_k<<<512, 256, 0, stream>>>(owb, ctxt, out_b, out);
}

// Round 7
// 292.641 us; speedup vs baseline: 1.0590x; 1.0590x over previous
//
#include <hip/hip_runtime.h>

using bf16x8 = __attribute__((ext_vector_type(8))) __bf16;
using f32x4  = __attribute__((ext_vector_type(4))) float;
using f32x16 = __attribute__((ext_vector_type(16))) float;
typedef __attribute__((ext_vector_type(2))) unsigned u32x2;
typedef __attribute__((ext_vector_type(4))) unsigned u32x4;

#define DEV __device__ __forceinline__

DEV unsigned short f2bf(float f){
  unsigned u = __builtin_bit_cast(unsigned, f);
  u += 0x7fffu + ((u >> 16) & 1u);
  return (unsigned short)(u >> 16);
}

DEV void load_lds16(const void* g, void* l){
  __builtin_amdgcn_global_load_lds((const __attribute__((address_space(1))) unsigned*)g,
                                   (__attribute__((address_space(3))) unsigned*)l, 16, 0, 0);
}

DEV f32x4 mfma16(bf16x8 a, bf16x8 b, f32x4 c){
  return __builtin_amdgcn_mfma_f32_16x16x32_bf16(a, b, c, 0, 0, 0);
}

DEV f32x16 mfma32(bf16x8 a, bf16x8 b, f32x16 c){
  return __builtin_amdgcn_mfma_f32_32x32x16_bf16(a, b, c, 0, 0, 0);
}

DEV float exp2_hw(float x){
  float r;
  asm("v_exp_f32 %0, %1" : "=v"(r) : "v"(x));
  return r;
}

DEV unsigned cvtpk_bf16(float a, float b){
  unsigned r;
  asm("v_cvt_pk_bf16_f32 %0, %1, %2" : "=v"(r) : "v"(a), "v"(b));
  return r;
}

DEV void permswap(unsigned &a, unsigned &b){
  asm volatile("v_permlane32_swap_b32 %0, %1" : "+v"(a), "+v"(b));
}

// ---------------- weight fp32 -> bf16 ----------------
__global__ void wconv_k(const float* __restrict__ a, unsigned short* __restrict__ o, int n4){
  for (int i = blockIdx.x * blockDim.x + threadIdx.x; i < n4; i += gridDim.x * blockDim.x){
    float4 v = reinterpret_cast<const float4*>(a)[i];
    ushort4 u;
    u.x = f2bf(v.x); u.y = f2bf(v.y); u.z = f2bf(v.z); u.w = f2bf(v.w);
    reinterpret_cast<ushort4*>(o)[i] = u;
  }
}

// ---------------- GroupNorm stats ----------------
__global__ __launch_bounds__(256) void gn_stats_k(const float* __restrict__ x, float* __restrict__ st){
  int bg = blockIdx.x; // b*32+g
  const float4* xp = reinterpret_cast<const float4*>(x + (size_t)bg * 32768);
  float s = 0.f, ss = 0.f;
  for (int i = threadIdx.x; i < 8192; i += 256){
    float4 v = xp[i];
    s  += (v.x + v.y) + (v.z + v.w);
    ss += (v.x*v.x + v.y*v.y) + (v.z*v.z + v.w*v.w);
  }
  #pragma unroll
  for (int off = 32; off; off >>= 1){ s += __shfl_down(s, off); ss += __shfl_down(ss, off); }
  __shared__ float rs[4], rss[4];
  if ((threadIdx.x & 63) == 0){ rs[threadIdx.x >> 6] = s; rss[threadIdx.x >> 6] = ss; }
  __syncthreads();
  if (threadIdx.x == 0){
    s  = (rs[0] + rs[1]) + (rs[2] + rs[3]);
    ss = (rss[0] + rss[1]) + (rss[2] + rss[3]);
    float mu  = s * (1.0f / 32768.0f);
    float var = ss * (1.0f / 32768.0f) - mu * mu;
    st[bg*2]   = mu;
    st[bg*2+1] = rsqrtf(var + 1e-5f);
  }
}

// ---------------- GN apply ----------------
__global__ __launch_bounds__(256) void gn_norm_k(const float* __restrict__ x,
                                                 const float* __restrict__ gw,
                                                 const float* __restrict__ gb,
                                                 const float* __restrict__ st,
                                                 float* __restrict__ xn,
                                                 unsigned short* __restrict__ xnt){
  int t = blockIdx.x;            // B*G*16 = 4096
  int tile = t & 15; int g = (t >> 4) & 31; int bb = t >> 9;
  float mu = st[(bb*32+g)*2], rstd = st[(bb*32+g)*2+1];
  __shared__ unsigned short lt[64*32];
  int tid = threadIdx.x;
  int l = tid & 63;
  int c0 = tid >> 6;
  size_t base = ((size_t)bb*1024 + g*32) * 1024 + tile*64;
  #pragma unroll
  for (int cb = 0; cb < 8; ++cb){
    int c = cb*4 + c0;
    size_t idx = base + (size_t)c*1024 + l;
    float xv = x[idx];
    int cg = g*32 + c;
    float v = (xv - mu) * rstd * gw[cg] + gb[cg];
    xn[idx] = v;
    lt[l*32 + c] = f2bf(v);
  }
  __syncthreads();
  int lr = tid >> 2, sl = tid & 3;
  uint4 u = *reinterpret_cast<uint4*>(&lt[lr*32 + sl*8]);
  size_t ob = ((size_t)bb*1024 + tile*64 + lr) * 1024 + g*32 + sl*8;
  *reinterpret_cast<uint4*>(&xnt[ob]) = u;
}

// ---------------- GEMM: 128x256 tile, BK=64, 8 waves, r4-skeleton dbuf pipeline ----------------
// C[M][N] = A[M][K] * Bt[N][K]^T. Per K-tile: 2 phases (ks halves) x 16 MFMA.
// Phase 0 stages ALL 6 loads of tile t+1 (4B + 2A); vmcnt(0) in phase 1 waits on
// loads issued >= 1 phase (~300cyc) earlier; one barrier pair per phase (r4-proven).
// Grid: MODE0 24x32=768 (3 even CU rounds), MODE1 8x32=256 (1/CU).
template<int MODE>
__global__ __launch_bounds__(512, 2) void gemmT_k(const unsigned short* __restrict__ A,
                                                  const unsigned short* __restrict__ Bm,
                                                  const float* __restrict__ bias,
                                                  float* __restrict__ outf,
                                                  unsigned short* __restrict__ qo,
                                                  unsigned short* __restrict__ ko,
                                                  unsigned short* __restrict__ vo){
  __shared__ char sA[2][16384];
  __shared__ char sB[2][32768];
  const int tid = threadIdx.x;
  const int w = tid >> 6, ln = tid & 63, hi = ln >> 4, lo = ln & 15;
  const int wm = w >> 2, wn = w & 3;              // 2M x 4N waves, per-wave 64x64
  const int bxo = (int)blockIdx.x;
  constexpr int MH = (MODE == 0 ? 12 : 4);        // mt per XCD chunk (2x4 chunk grid)
  const int xcd = bxo & 7, idx = bxo >> 3;
  const int mt = (xcd >> 2)*MH + idx % MH;
  const int nt = (xcd & 3)*8 + idx / MH;
  const char* Ag = (const char*)A + (size_t)mt*128*2048;
  const char* Bg = (const char*)Bm + (size_t)nt*256*2048;
  f32x4 acc[4][4] = {};

  auto stageA = [&](int buf, int kt, int i){
    int s = tid*16 + i*8192;
    int row = s >> 7;
    int byte = (s & 127) ^ ((row & 7) << 4);
    load_lds16(Ag + (size_t)row*2048 + kt*128 + byte, sA[buf] + s);
  };
  auto stageB = [&](int buf, int kt, int i){
    int s = tid*16 + i*8192;
    int row = s >> 7;
    int byte = (s & 127) ^ ((row & 7) << 4);
    load_lds16(Bg + (size_t)row*2048 + kt*128 + byte, sB[buf] + s);
  };

  // prologue: stage tile 0
  stageB(0,0,0); stageB(0,0,1); stageB(0,0,2); stageB(0,0,3);
  stageA(0,0,0); stageA(0,0,1);
  asm volatile("s_waitcnt vmcnt(0)" ::: "memory");
  __builtin_amdgcn_s_barrier();

  for (int t = 0; t < 16; ++t){
    const int cur = t & 1, nxt = cur ^ 1;
    const bool st = (t < 15);
    const char* sAc = sA[cur];
    const char* sBc = sB[cur];
    bf16x8 a[4], b[4];

    // ---- phase 0: ks = 0; stage all 6 loads of tile t+1 ----
    #pragma unroll
    for (int mi = 0; mi < 4; ++mi){
      int row = wm*64 + mi*16 + lo;
      a[mi] = *reinterpret_cast<const bf16x8*>(sAc + row*128 + ((hi*16) ^ ((row & 7) << 4)));
    }
    #pragma unroll
    for (int ni = 0; ni < 4; ++ni){
      int row = wn*64 + ni*16 + lo;
      b[ni] = *reinterpret_cast<const bf16x8*>(sBc + row*128 + ((hi*16) ^ ((row & 7) << 4)));
    }
    if (st){
      stageB(nxt,t+1,0); stageB(nxt,t+1,1); stageB(nxt,t+1,2); stageB(nxt,t+1,3);
      stageA(nxt,t+1,0); stageA(nxt,t+1,1);
    }
    __builtin_amdgcn_s_barrier();
    __builtin_amdgcn_s_setprio(1);
    #pragma unroll
    for (int mi = 0; mi < 4; ++mi)
      #pragma unroll
      for (int ni = 0; ni < 4; ++ni)
        acc[mi][ni] = mfma16(a[mi], b[ni], acc[mi][ni]);
    __builtin_amdgcn_s_setprio(0);
    __builtin_amdgcn_s_barrier();

    // ---- phase 1: ks = 1; drain next-tile loads before final barrier ----
    #pragma unroll
    for (int mi = 0; mi < 4; ++mi){
      int row = wm*64 + mi*16 + lo;
      a[mi] = *reinterpret_cast<const bf16x8*>(sAc + row*128 + ((64 + hi*16) ^ ((row & 7) << 4)));
    }
    #pragma unroll
    for (int ni = 0; ni < 4; ++ni){
      int row = wn*64 + ni*16 + lo;
      b[ni] = *reinterpret_cast<const bf16x8*>(sBc + row*128 + ((64 + hi*16) ^ ((row & 7) << 4)));
    }
    __builtin_amdgcn_s_barrier();
    __builtin_amdgcn_s_setprio(1);
    #pragma unroll
    for (int mi = 0; mi < 4; ++mi)
      #pragma unroll
      for (int ni = 0; ni < 4; ++ni)
        acc[mi][ni] = mfma16(a[mi], b[ni], acc[mi][ni]);
    __builtin_amdgcn_s_setprio(0);
    if (st) asm volatile("s_waitcnt vmcnt(0)" ::: "memory");
    __builtin_amdgcn_s_barrier();
  }

  // ---- epilogue ----
  const int b8 = nt >> 2;
  if (MODE == 0){
    #pragma unroll
    for (int mi = 0; mi < 4; ++mi){
      const int o0 = mt*128 + wm*64 + mi*16 + hi*4;
      const int hh = o0 / 192;
      const int rr = o0 % 192;
      const size_t hb = (size_t)b8*16 + hh;
      float bv0 = bias[o0], bv1 = bias[o0+1], bv2 = bias[o0+2], bv3 = bias[o0+3];
      #pragma unroll
      for (int ni = 0; ni < 4; ++ni){
        const int l = (nt & 3)*256 + wn*64 + ni*16 + lo;
        f32x4 v = acc[mi][ni];
        if (rr < 64){
          ushort4 u;
          u.x = f2bf(v[0] + bv0); u.y = f2bf(v[1] + bv1);
          u.z = f2bf(v[2] + bv2); u.w = f2bf(v[3] + bv3);
          *reinterpret_cast<ushort4*>(qo + (hb*1024 + l)*64 + rr) = u;
        } else if (rr < 128){
          ushort4 u;
          u.x = f2bf(v[0] + bv0); u.y = f2bf(v[1] + bv1);
          u.z = f2bf(v[2] + bv2); u.w = f2bf(v[3] + bv3);
          *reinterpret_cast<ushort4*>(ko + (hb*1024 + l)*64 + (rr - 64)) = u;
        } else {
          const int d = rr - 128;
          vo[(hb*64 + d + 0)*1024 + l] = f2bf(v[0] + bv0);
          vo[(hb*64 + d + 1)*1024 + l] = f2bf(v[1] + bv1);
          vo[(hb*64 + d + 2)*1024 + l] = f2bf(v[2] + bv2);
          vo[(hb*64 + d + 3)*1024 + l] = f2bf(v[3] + bv3);
        }
      }
    }
  } else {
    #pragma unroll
    for (int mi = 0; mi < 4; ++mi){
      const int o0 = mt*128 + wm*64 + mi*16 + hi*4;
      #pragma unroll
      for (int ni = 0; ni < 4; ++ni){
        const int l = (nt & 3)*256 + wn*64 + ni*16 + lo;
        #pragma unroll
        for (int r = 0; r < 4; ++r){
          size_t idx2 = ((size_t)b8*1024 + o0 + r) * 1024 + l;
          outf[idx2] += acc[mi][ni][r] + bias[o0 + r];
        }
      }
    }
  }
}

// ---------------- flash attention: swapped QK^T 32x32, in-register softmax ----------------
__global__ __launch_bounds__(256) void attn_k(const unsigned short* __restrict__ qt,
                                              const unsigned short* __restrict__ kt,
                                              const unsigned short* __restrict__ vt,
                                              unsigned short* __restrict__ ctx){
  __shared__ char sK[2][8192];
  __shared__ char sV[2][8192];
  __shared__ float sRed[4][32];
  const int tid = threadIdx.x;
  const int w = tid >> 6, ln = tid & 63;
  const int hi5 = ln >> 5, lo5 = ln & 31;
  const int bxo = (int)blockIdx.x;
  const int bx = (bxo & 7) * 128 + (bxo >> 3);   // XCD swizzle
  const int qb = bx & 7;
  const int bh = bx >> 3;                        // b*16 + h
  const unsigned short* qp = qt + ((size_t)bh*1024 + qb*128 + w*32 + lo5) * 64;
  bf16x8 qreg[4];
  #pragma unroll
  for (int d = 0; d < 4; ++d)
    qreg[d] = *reinterpret_cast<const bf16x8*>(qp + d*16 + hi5*8);
  const char* kg = (const char*)(kt + (size_t)bh*65536);
  const char* vg = (const char*)(vt + (size_t)bh*65536);
  f32x16 oa0 = {}, oa1 = {};
  float m = 0.f, l = 0.f;

  auto STAGE = [&](int buf, int kb){
    #pragma unroll
    for (int i = 0; i < 2; ++i){
      int s = tid*16 + i*4096;
      int row = s >> 7;
      int byte = (s & 127) ^ ((row & 7) << 4);
      load_lds16(kg + (size_t)(kb*64 + row)*128 + byte, sK[buf] + s);
      load_lds16(vg + (size_t)row*2048 + kb*128 + byte, sV[buf] + s);
    }
  };

  const float sc2 = 0.015625f * 1.44269504f;  // (1/64) * log2(e)

  STAGE(0, 0);
  asm volatile("s_waitcnt vmcnt(0)" ::: "memory");
  __builtin_amdgcn_s_barrier();

  for (int kb = 0; kb < 16; ++kb){
    const int cur = kb & 1;
    STAGE(cur ^ 1, (kb + 1) & 15);

    const char* kbase0 = sK[cur] + lo5*128;
    const char* kbase1 = sK[cur] + (32 + lo5)*128;
    const int ksw = (lo5 & 7) << 4;
    f32x16 s0 = {}, s1 = {};
    #pragma unroll
    for (int d = 0; d < 4; ++d){
      int off = (d*32 + hi5*16) ^ ksw;
      bf16x8 ka = *reinterpret_cast<const bf16x8*>(kbase0 + off);
      bf16x8 kb8 = *reinterpret_cast<const bf16x8*>(kbase1 + off);
      s0 = mfma32(ka, qreg[d], s0);
      s1 = mfma32(kb8, qreg[d], s1);
    }

    float t[16];
    #pragma unroll
    for (int i = 0; i < 16; ++i) t[i] = fmaxf(s0[i], s1[i]);
    #pragma unroll
    for (int st = 8; st; st >>= 1)
      #pragma unroll
      for (int i = 0; i < st; ++i) t[i] = fmaxf(t[i], t[i+st]);
    float mx = fmaxf(t[0], __shfl_xor(t[0], 32));
    float m2 = mx * sc2;

    if (__builtin_expect(__any(m2 > m + 8.f), 0)){
      float nm = fmaxf(m, m2);
      float corr = exp2_hw(m - nm);
      m = nm; l *= corr;
      sRed[w][lo5] = corr;
      __builtin_amdgcn_wave_barrier();
      #pragma unroll
      for (int r = 0; r < 16; ++r){
        float cc = sRed[w][(r & 3) + 8*(r >> 2) + 4*hi5];
        oa0[r] *= cc; oa1[r] *= cc;
      }
      __builtin_amdgcn_wave_barrier();
    }

    float ps[16];
    #pragma unroll
    for (int i = 0; i < 16; ++i){
      float p0 = exp2_hw(fmaf(s0[i], sc2, -m));
      float p1 = exp2_hw(fmaf(s1[i], sc2, -m));
      s0[i] = p0; s1[i] = p1;
      ps[i] = p0 + p1;
    }
    #pragma unroll
    for (int st = 8; st; st >>= 1)
      #pragma unroll
      for (int i = 0; i < st; ++i) ps[i] += ps[i+st];
    l += ps[0] + __shfl_xor(ps[0], 32);

    bf16x8 pa[4];
    #pragma unroll
    for (int sl = 0; sl < 4; ++sl){
      const int c0 = 2*(sl & 1), c1 = c0 + 1;
      unsigned w0, w1, w2, w3;
      if (sl < 2){
        w0 = cvtpk_bf16(s0[4*c0+0], s0[4*c0+1]);
        w1 = cvtpk_bf16(s0[4*c0+2], s0[4*c0+3]);
        w2 = cvtpk_bf16(s0[4*c1+0], s0[4*c1+1]);
        w3 = cvtpk_bf16(s0[4*c1+2], s0[4*c1+3]);
      } else {
        w0 = cvtpk_bf16(s1[4*c0+0], s1[4*c0+1]);
        w1 = cvtpk_bf16(s1[4*c0+2], s1[4*c0+3]);
        w2 = cvtpk_bf16(s1[4*c1+0], s1[4*c1+1]);
        w3 = cvtpk_bf16(s1[4*c1+2], s1[4*c1+3]);
      }
      permswap(w0, w2);
      permswap(w1, w3);
      u32x4 pc; pc.x = w0; pc.y = w1; pc.z = w2; pc.w = w3;
      pa[sl] = __builtin_bit_cast(bf16x8, pc);
    }

    const char* vb0 = sV[cur] + lo5*128;
    const char* vb1 = sV[cur] + (32 + lo5)*128;
    #pragma unroll
    for (int sl = 0; sl < 4; ++sl){
      int off = (sl*32 + hi5*16) ^ ksw;
      bf16x8 v0 = *reinterpret_cast<const bf16x8*>(vb0 + off);
      bf16x8 v1 = *reinterpret_cast<const bf16x8*>(vb1 + off);
      oa0 = mfma32(pa[sl], v0, oa0);
      oa1 = mfma32(pa[sl], v1, oa1);
    }

    asm volatile("s_waitcnt vmcnt(0)" ::: "memory");
    __builtin_amdgcn_s_barrier();
  }

  sRed[w][lo5] = l;
  __builtin_amdgcn_wave_barrier();
  const int b = bh >> 4, h = bh & 15;
  #pragma unroll
  for (int r = 0; r < 16; ++r){
    int ql = (r & 3) + 8*(r >> 2) + 4*hi5;
    float inv = __builtin_amdgcn_rcpf(sRed[w][ql]);
    size_t rowb = ((size_t)b*1024 + qb*128 + w*32 + ql) * 1024 + h*64;
    ctx[rowb + lo5]      = f2bf(oa0[r] * inv);
    ctx[rowb + 32 + lo5] = f2bf(oa1[r] * inv);
  }
}

extern "C" void kernel_launch(void* const* d_in, const int* in_sizes, int n_in,
                              void* d_out, int out_size, void* d_ws, size_t ws_size,
                              hipStream_t stream) {
  (void)in_sizes; (void)n_in; (void)out_size; (void)ws_size;
  const float* x     = (const float*)d_in[0];
  const float* gn_w  = (const float*)d_in[1];
  const float* gn_b  = (const float*)d_in[2];
  const float* qkv_w = (const float*)d_in[3];
  const float* qkv_b = (const float*)d_in[4];
  const float* out_w = (const float*)d_in[5];
  const float* out_b = (const float*)d_in[6];
  // d_in[7] = qk_bias scalar: softmax(x+c)==softmax(x) -> no-op.
  float* out = (float*)d_out;
  char* ws = (char*)d_ws;
  unsigned short* xnt  = (unsigned short*)(ws);               // 16 MiB  xn^T  [b][l][c]
  unsigned short* qwb  = (unsigned short*)(ws + 16777216);    // 6 MiB   qkv_w bf16
  unsigned short* owb  = (unsigned short*)(ws + 23068672);    // 2 MiB   out_w bf16
  unsigned short* qt   = (unsigned short*)(ws + 25165824);    // 16 MiB  q [b][h][l][d]
  unsigned short* kt   = (unsigned short*)(ws + 41943040);    // 16 MiB  k [b][h][l][d]
  unsigned short* vs   = (unsigned short*)(ws + 58720256);    // 16 MiB  v [b][h][d][l]
  unsigned short* ctxt = (unsigned short*)(ws + 75497472);    // 16 MiB  ctx^T [b][l][c]
  float*          st   = (float*)(ws + 92274688);             // 2 KiB   GN stats

  wconv_k<<<512, 256, 0, stream>>>(qkv_w, qwb, 786432);
  wconv_k<<<512, 256, 0, stream>>>(out_w, owb, 262144);
  gn_stats_k<<<256, 256, 0, stream>>>(x, st);
  gn_norm_k<<<4096, 256, 0, stream>>>(x, gn_w, gn_b, st, out, xnt);
  gemmT_k<0><<<768, 512, 0, stream>>>(qwb, xnt, qkv_b, nullptr, qt, kt, vs);
  attn_k<<<1024, 256, 0, stream>>>(qt, kt, vs, ctxt);
  gemmT_k<1><<<256, 512, 0, stream>>>(owb, ctxt, out_b, out, nullptr, nullptr, nullptr);
}